// Round 6
// baseline (37.999 us; speedup 1.0000x reference)
//
#include <hip/hip_runtime.h>

// embedding: (32, 512, 32, 32) f32 ; pixel_shuffle r=4 -> x_ps (32, 32, 128, 128)
// conv 3x3 pad1 (32->32) + BN + ReLU ; head: 32->4 relu -> 1 ; sigmoid
// concat [sig, mask] -> 5x5 conv pad2 (2->1) ; out (32,1,128,128) f32
//
// v6: v5 + true 16-deep load MLP in staging:
//   - all 16 global_load_dwordx4 issued back-to-back (sched_barrier(0) fence,
//     acc/addr work moved after the barrier so prefetch regs dominate live set)
//   - theory: v5 was memory-LATENCY-bound (941 GB/s achieved, VGPR=60 proved
//     the compiler serialized the prefetch). Forcing 64 live VGPRs of prefetch
//     restores MLP=16/thread.

typedef __attribute__((ext_vector_type(8))) short short8;
typedef __attribute__((ext_vector_type(4))) float f32x4;

static __device__ __forceinline__ ushort f2bf(float x) {
    union { float f; uint u; } v; v.f = x;
    uint r = v.u + 0x7fffu + ((v.u >> 16) & 1u);   // round-nearest-even
    return (ushort)(r >> 16);
}
static __device__ __forceinline__ uint cvt_pk_bf16(float lo, float hi) {
    uint r;
    asm("v_cvt_pk_bf16_f32 %0, %1, %2" : "=v"(r) : "v"(lo), "v"(hi));
    return r;   // {hi=bf16(hi), lo=bf16(lo)}
}

#define SIG_ELEMS (32 * 128 * 128)
#define BFRAG_OFF (SIG_ELEMS * 4)            // bytes into d_ws
#define SC_OFF    (BFRAG_OFF + 18432)
#define SH_OFF    (SC_OFF + 128)

// ---- prep: pack B fragments (bf16) + fold BN into sc/sh tables ----
__global__ void prep_kernel(const float* __restrict__ conv_w,
                            const float* __restrict__ conv_b,
                            const float* __restrict__ bn_gamma,
                            const float* __restrict__ bn_beta,
                            const float* __restrict__ bn_mean,
                            const float* __restrict__ bn_var,
                            ushort* __restrict__ bfrag,   // [18][64][8]
                            float* __restrict__ scb, float* __restrict__ shb) {
    int t = blockIdx.x * 256 + threadIdx.x;
    if (t < 9216) {
        int j    = t & 7;
        int lane = (t >> 3) & 63;
        int knt  = t >> 9;          // 0..17 = kk*2 + nt
        int kk   = knt >> 1;        // tap p
        int nt   = knt & 1;
        int oc   = (lane & 15) + nt * 16;
        int c    = (lane >> 4) * 8 + j;
        bfrag[t] = f2bf(conv_w[oc * 288 + c * 9 + kk]);
    } else if (t < 9248) {
        int oc = t - 9216;
        float sc = bn_gamma[oc] * rsqrtf(bn_var[oc] + 1e-5f);
        scb[oc] = sc;
        shb[oc] = (conv_b[oc] - bn_mean[oc]) * sc + bn_beta[oc];
    }
}

// ---- main: implicit-GEMM conv + BN + ReLU + head + sigmoid ----
#define PITCHB 8320          // 130 cells * 64 B per staged row
#define HPITCH 36            // fp32 bounce pitch (144 B: 16B-aligned rows)

__global__ __launch_bounds__(256, 4) void fused_main_kernel(
    const float* __restrict__ emb,      // (32,512,32,32)
    const float* __restrict__ inc,      // (32,137)
    const ushort* __restrict__ bfrag,   // [18][64][8] bf16
    const float* __restrict__ scb,
    const float* __restrict__ shb,
    float* __restrict__ sig_out)        // (32,128,128)
{
    __shared__ __align__(16) char smem[256 * HPITCH * 4];   // 36864 B >= 4*PITCHB

    const int bid = blockIdx.x;
    const int lid = (bid & 7) * 256 + (bid >> 3);     // XCD swizzle (2048=8*256)
    const int n    = lid >> 6;     // image
    const int band = lid & 63;     // 2-row band
    const int h0   = band << 1;

    const int tid  = threadIdx.x;

    // ---- staging phase A: issue ALL 16 global loads back-to-back ----
    float4 pre0[8], pre1[8];
    #pragma unroll
    for (int k = 0; k < 8; ++k) {
        int u  = tid + (k << 8);       // 0..2047
        int f  = u & 7;
        int sx = (u >> 3) & 3;
        int cp = (u >> 5) & 15;
        int y  = u >> 9;
        int h  = h0 + y - 1;
        pre0[k] = make_float4(0.f, 0.f, 0.f, 0.f);
        pre1[k] = pre0[k];
        if ((unsigned)h < 128u) {
            int cc0  = cp * 32 + ((h & 3) << 2) + sx;
            long base = ((long)(n * 512 + cc0) << 10) + ((h >> 2) << 5) + (f << 2);
            pre0[k] = *reinterpret_cast<const float4*>(&emb[base]);
            pre1[k] = *reinterpret_cast<const float4*>(&emb[base + (16 << 10)]);
        }
    }
    __builtin_amdgcn_sched_barrier(0);   // pin: all 16 loads issued before any use

    // Halo-zero (xi=0, xi=129) — LDS-only, overlaps load latency.
    if (tid < 128) {
        int y   = tid >> 5;
        int col = (tid >> 4) & 1;
        int wrd = tid & 15;
        ((uint*)smem)[(y * PITCHB + (col ? 129 : 0) * 64) / 4 + wrd] = 0u;
    }

    // ---- staging phase B: convert (cvt_pk) + swizzled scatter to LDS ----
    #pragma unroll
    for (int k = 0; k < 8; ++k) {
        int u  = tid + (k << 8);
        int f  = u & 7;
        int sx = (u >> 3) & 3;
        int cp = (u >> 5) & 15;
        int y  = u >> 9;
        uint pk0 = cvt_pk_bf16(pre0[k].x, pre1[k].x);
        uint pk1 = cvt_pk_bf16(pre0[k].y, pre1[k].y);
        uint pk2 = cvt_pk_bf16(pre0[k].z, pre1[k].z);
        uint pk3 = cvt_pk_bf16(pre0[k].w, pre1[k].w);
        const uint pks[4] = {pk0, pk1, pk2, pk3};
        #pragma unroll
        for (int e = 0; e < 4; ++e) {
            int xi   = 1 + sx + (f << 4) + (e << 2);   // staged col 1..128
            int slot = ((cp >> 2) ^ ((xi >> 1) ^ (xi >> 4))) & 3;
            ((uint*)smem)[(y * PITCHB + xi * 64 + (slot << 4) + ((cp & 3) << 2)) / 4] = pks[e];
        }
    }
    __syncthreads();

    // MFMA-side decomposition (computed after staging: keeps staging live-set small)
    const int lane = tid & 63;
    const int wv   = tid >> 6;
    const int g    = lane >> 4;    // c_high group
    const int m    = lane & 15;    // A row (pixel) / C col (oc)
    const int rw   = wv >> 1;      // wave's output row (0/1)
    const int xq   = (wv & 1) * 64;

    // A-fragment addresses: 4 tiles x 3 dx.
    int adr[4][3];
    #pragma unroll
    for (int t = 0; t < 4; ++t)
        #pragma unroll
        for (int dx = 0; dx < 3; ++dx) {
            int xi = xq + t * 16 + m + dx;
            int slot = (g ^ ((xi >> 1) ^ (xi >> 4))) & 3;
            adr[t][dx] = rw * PITCHB + xi * 64 + (slot << 4);
        }

    f32x4 acc[4][2];
    #pragma unroll
    for (int t = 0; t < 4; ++t)
        #pragma unroll
        for (int nt = 0; nt < 2; ++nt)
            acc[t][nt] = (f32x4){0.f, 0.f, 0.f, 0.f};

    #pragma unroll
    for (int kk = 0; kk < 9; ++kk) {
        const int dy = kk / 3, dxs = kk % 3;
        short8 b0 = *reinterpret_cast<const short8*>(bfrag + (((kk * 2 + 0) * 64 + lane) << 3));
        short8 b1 = *reinterpret_cast<const short8*>(bfrag + (((kk * 2 + 1) * 64 + lane) << 3));
        #pragma unroll
        for (int t = 0; t < 4; ++t) {
            short8 a = *reinterpret_cast<const short8*>(&smem[adr[t][dxs] + dy * PITCHB]);
            acc[t][0] = __builtin_amdgcn_mfma_f32_16x16x32_bf16(a, b0, acc[t][0], 0, 0, 0);
            acc[t][1] = __builtin_amdgcn_mfma_f32_16x16x32_bf16(a, b1, acc[t][1], 0, 0, 0);
        }
    }

    // Epilogue 1: BN + ReLU -> fp32 LDS bounce [px][HPITCH].
    __syncthreads();   // everyone done reading the A tile
    {
        float* lb = (float*)smem;
        float sc0 = scb[m],      sh0 = shb[m];
        float sc1 = scb[m + 16], sh1 = shb[m + 16];
        #pragma unroll
        for (int t = 0; t < 4; ++t) {
            int pxb = rw * 128 + xq + t * 16 + g * 4;
            #pragma unroll
            for (int nt = 0; nt < 2; ++nt) {
                int oc = nt * 16 + m;
                float sc = nt ? sc1 : sc0, sh = nt ? sh1 : sh0;
                f32x4 A = acc[t][nt];
                lb[(pxb + 0) * HPITCH + oc] = fmaxf(fmaf(A.x, sc, sh), 0.f);
                lb[(pxb + 1) * HPITCH + oc] = fmaxf(fmaf(A.y, sc, sh), 0.f);
                lb[(pxb + 2) * HPITCH + oc] = fmaxf(fmaf(A.z, sc, sh), 0.f);
                lb[(pxb + 3) * HPITCH + oc] = fmaxf(fmaf(A.w, sc, sh), 0.f);
            }
        }
    }
    __syncthreads();

    // Epilogue 2: per-pixel head (1 thread = 1 pixel), b128 reads, sigmoid.
    {
        const f32x4* row = reinterpret_cast<const f32x4*>((float*)smem + tid * HPITCH);
        f32x4 xv[8];
        #pragma unroll
        for (int q = 0; q < 8; ++q) xv[q] = row[q];

        const float* hd = inc + n * 137;
        float y = hd[136];
        #pragma unroll
        for (int o = 0; o < 4; ++o) {
            float hv = hd[132 + o];
            #pragma unroll
            for (int q = 0; q < 8; ++q) {
                hv = fmaf(hd[o * 32 + q * 4 + 0], xv[q].x, hv);
                hv = fmaf(hd[o * 32 + q * 4 + 1], xv[q].y, hv);
                hv = fmaf(hd[o * 32 + q * 4 + 2], xv[q].z, hv);
                hv = fmaf(hd[o * 32 + q * 4 + 3], xv[q].w, hv);
            }
            hv = fmaxf(hv, 0.0f);
            y = fmaf(hd[128 + o], hv, y);
        }
        float s = 1.0f / (1.0f + __expf(-y));
        int row_i = tid >> 7, x = tid & 127;
        sig_out[(n << 14) + ((h0 + row_i) << 7) + x] = s;
    }
}

// ---- smooth: 5x5, 2ch -> 1ch ----
__global__ __launch_bounds__(256) void smooth_kernel(
    const float* __restrict__ sig,
    const float* __restrict__ masks,
    const float* __restrict__ sw,
    const float* __restrict__ sb,
    float* __restrict__ out)
{
    __shared__ float ls[2][400];

    const int tid  = threadIdx.x;
    const int n    = blockIdx.x >> 6;
    const int tile = blockIdx.x & 63;
    const int h0   = (tile >> 3) << 4;
    const int w0   = (tile & 7) << 4;

    for (int i = tid; i < 800; i += 256) {
        int chn = (i >= 400) ? 1 : 0;
        int r  = i - chn * 400;
        int yy = r / 20;
        int xx = r - yy * 20;
        int h  = h0 + yy - 2;
        int w  = w0 + xx - 2;
        float v = 0.0f;
        if ((unsigned)h < 128u && (unsigned)w < 128u) {
            const float* src = chn ? masks : sig;
            v = src[(n << 14) + (h << 7) + w];
        }
        ls[chn][r] = v;
    }
    __syncthreads();

    const int tx = tid & 15;
    const int ty = tid >> 4;

    float accv = sb[0];
    #pragma unroll
    for (int chn = 0; chn < 2; ++chn)
        #pragma unroll
        for (int dy = 0; dy < 5; ++dy)
            #pragma unroll
            for (int dx = 0; dx < 5; ++dx)
                accv = fmaf(ls[chn][(ty + dy) * 20 + tx + dx],
                            sw[(chn * 5 + dy) * 5 + dx], accv);
    out[(n << 14) + ((h0 + ty) << 7) + (w0 + tx)] = accv;
}

extern "C" void kernel_launch(void* const* d_in, const int* in_sizes, int n_in,
                              void* d_out, int out_size, void* d_ws, size_t ws_size,
                              hipStream_t stream) {
    const float* emb     = (const float*)d_in[0];
    const float* inc     = (const float*)d_in[1];
    const float* masks   = (const float*)d_in[2];
    const float* conv_w  = (const float*)d_in[3];
    const float* conv_b  = (const float*)d_in[4];
    const float* bn_g    = (const float*)d_in[5];
    const float* bn_b    = (const float*)d_in[6];
    const float* bn_m    = (const float*)d_in[7];
    const float* bn_v    = (const float*)d_in[8];
    const float* sw      = (const float*)d_in[9];
    const float* sb      = (const float*)d_in[10];
    float*  out   = (float*)d_out;
    float*  sig   = (float*)d_ws;
    ushort* bfrag = (ushort*)((char*)d_ws + BFRAG_OFF);
    float*  scb   = (float*)((char*)d_ws + SC_OFF);
    float*  shb   = (float*)((char*)d_ws + SH_OFF);

    prep_kernel<<<37, 256, 0, stream>>>(conv_w, conv_b, bn_g, bn_b, bn_m, bn_v,
                                        bfrag, scb, shb);
    fused_main_kernel<<<2048, 256, 0, stream>>>(emb, inc, bfrag, scb, shb, sig);
    smooth_kernel<<<2048, 256, 0, stream>>>(sig, masks, sw, sb, out);
}

// Round 7
// 36.606 us; speedup vs baseline: 1.0380x; 1.0380x over previous
//
#include <hip/hip_runtime.h>

// embedding: (32, 512, 32, 32) f32 ; pixel_shuffle r=4 -> x_ps (32, 32, 128, 128)
// conv 3x3 pad1 (32->32) + BN + ReLU ; head: 32->4 relu -> 1 ; sigmoid
// concat [sig, mask] -> 5x5 conv pad2 (2->1) ; out (32,1,128,128) f32
//
// v7: swap MFMA operands -> C[oc][px]: head computed in-register via
//     butterfly shfl (epilogue LDS bounce + 2 barriers GONE); staging
//     writes become ds_write_b128 (4 cplo per thread per slot); BN scale
//     folded into bfrag; head params repacked aligned in prep.

typedef __attribute__((ext_vector_type(8))) short short8;
typedef __attribute__((ext_vector_type(4))) float f32x4;

static __device__ __forceinline__ ushort f2bf(float x) {
    union { float f; uint u; } v; v.f = x;
    uint r = v.u + 0x7fffu + ((v.u >> 16) & 1u);   // round-nearest-even
    return (ushort)(r >> 16);
}
static __device__ __forceinline__ uint cvt_pk_bf16(float lo, float hi) {
    uint r;
    asm("v_cvt_pk_bf16_f32 %0, %1, %2" : "=v"(r) : "v"(lo), "v"(hi));
    return r;   // {hi=bf16(hi), lo=bf16(lo)}
}

#define SIG_ELEMS (32 * 128 * 128)
#define BFRAG_OFF (SIG_ELEMS * 4)          // bytes into d_ws, 16B aligned
#define SH_OFF    (BFRAG_OFF + 18432)
#define HDP_OFF   (SH_OFF + 128)           // padded head params [32][144]

// ---- prep: pack B fragments (bf16, BN-scale folded) + shift + head repack ----
__global__ void prep_kernel(const float* __restrict__ conv_w,
                            const float* __restrict__ conv_b,
                            const float* __restrict__ bn_gamma,
                            const float* __restrict__ bn_beta,
                            const float* __restrict__ bn_mean,
                            const float* __restrict__ bn_var,
                            const float* __restrict__ inc,
                            ushort* __restrict__ bfrag,   // [18][64][8]
                            float* __restrict__ shb,      // [32]
                            float* __restrict__ hdp) {    // [32][144]
    int t = blockIdx.x * 256 + threadIdx.x;
    if (t < 9216) {
        int j    = t & 7;
        int lane = (t >> 3) & 63;
        int knt  = t >> 9;          // kk*2 + nt
        int kk   = knt >> 1;
        int nt   = knt & 1;
        int oc   = (lane & 15) + nt * 16;
        int c    = (lane >> 4) * 8 + j;
        float sc = bn_gamma[oc] * rsqrtf(bn_var[oc] + 1e-5f);
        bfrag[t] = f2bf(conv_w[oc * 288 + c * 9 + kk] * sc);
    } else if (t < 9248) {
        int oc = t - 9216;
        float sc = bn_gamma[oc] * rsqrtf(bn_var[oc] + 1e-5f);
        shb[oc] = (conv_b[oc] - bn_mean[oc]) * sc + bn_beta[oc];
    } else if (t < 9248 + 32 * 137) {
        int i = t - 9248;
        int nn = i / 137, r = i - nn * 137;
        hdp[nn * 144 + r] = inc[i];
    }
}

// ---- main: implicit-GEMM conv + BN + ReLU + head + sigmoid ----
#define PITCHB 8320          // 130 cells * 64 B per staged row

__global__ __launch_bounds__(256, 4) void fused_main_kernel(
    const float* __restrict__ emb,      // (32,512,32,32)
    const ushort* __restrict__ bfrag,   // [18][64][8] bf16 (scale-folded)
    const float* __restrict__ shb,      // [32]
    const float* __restrict__ hdp,      // [32][144]
    float* __restrict__ sig_out)        // (32,128,128)
{
    __shared__ __align__(16) char smem[4 * PITCHB];   // 33280 B

    const int bid = blockIdx.x;
    const int lid = (bid & 7) * 256 + (bid >> 3);     // XCD swizzle (2048=8*256)
    const int n    = lid >> 6;     // image
    const int band = lid & 63;     // 2-row band
    const int h0   = band << 1;

    const int tid  = threadIdx.x;

    // Staging decomposition: thread = (f, cphi, sx) x rows {yA, yB=yA+2}.
    const int f    = tid & 7;
    const int cphi = (tid >> 3) & 3;
    const int sx   = (tid >> 5) & 3;
    const int yA   = tid >> 7;         // 0..1
    const int yB   = yA + 2;           // 2..3
    const int hA   = h0 + yA - 1;
    const int hB   = h0 + yB - 1;
    const bool vA  = (unsigned)hA < 128u;
    const bool vB  = (unsigned)hB < 128u;

    // Phase A: issue all 16 global loads (4 cplo x 2 img-halves x 2 rows).
    float4 pA0[4], pA1[4], pB0[4], pB1[4];
    #pragma unroll
    for (int cplo = 0; cplo < 4; ++cplo) {
        pA0[cplo] = make_float4(0.f, 0.f, 0.f, 0.f);
        pA1[cplo] = pA0[cplo]; pB0[cplo] = pA0[cplo]; pB1[cplo] = pA0[cplo];
        if (vA) {
            int cc = cphi * 128 + cplo * 32 + ((hA & 3) << 2) + sx;
            long base = ((long)(n * 512 + cc) << 10) + ((hA >> 2) << 5) + (f << 2);
            pA0[cplo] = *reinterpret_cast<const float4*>(&emb[base]);
            pA1[cplo] = *reinterpret_cast<const float4*>(&emb[base + (16 << 10)]);
        }
        if (vB) {
            int cc = cphi * 128 + cplo * 32 + ((hB & 3) << 2) + sx;
            long base = ((long)(n * 512 + cc) << 10) + ((hB >> 2) << 5) + (f << 2);
            pB0[cplo] = *reinterpret_cast<const float4*>(&emb[base]);
            pB1[cplo] = *reinterpret_cast<const float4*>(&emb[base + (16 << 10)]);
        }
    }
    __builtin_amdgcn_sched_barrier(0);

    // Halo-zero columns xi=0 and xi=129 (overlaps load latency).
    if (tid < 128) {
        int y   = tid >> 5;
        int col = (tid >> 4) & 1;
        int wrd = tid & 15;
        ((uint*)smem)[(y * PITCHB + (col ? 129 : 0) * 64) / 4 + wrd] = 0u;
    }

    // Phase B: pack 4 cplo into one b128 write per (row, e).
    #pragma unroll
    for (int e = 0; e < 4; ++e) {
        int xi   = 1 + sx + (f << 4) + (e << 2);
        int slot = (cphi ^ ((xi >> 1) ^ (xi >> 4))) & 3;
        int off  = xi * 64 + (slot << 4);
        const float a00[4] = {pA0[0].x, pA0[0].y, pA0[0].z, pA0[0].w};
        const float a01[4] = {pA0[1].x, pA0[1].y, pA0[1].z, pA0[1].w};
        const float a02[4] = {pA0[2].x, pA0[2].y, pA0[2].z, pA0[2].w};
        const float a03[4] = {pA0[3].x, pA0[3].y, pA0[3].z, pA0[3].w};
        const float a10[4] = {pA1[0].x, pA1[0].y, pA1[0].z, pA1[0].w};
        const float a11[4] = {pA1[1].x, pA1[1].y, pA1[1].z, pA1[1].w};
        const float a12[4] = {pA1[2].x, pA1[2].y, pA1[2].z, pA1[2].w};
        const float a13[4] = {pA1[3].x, pA1[3].y, pA1[3].z, pA1[3].w};
        uint4 qa;
        qa.x = cvt_pk_bf16(a00[e], a10[e]);
        qa.y = cvt_pk_bf16(a01[e], a11[e]);
        qa.z = cvt_pk_bf16(a02[e], a12[e]);
        qa.w = cvt_pk_bf16(a03[e], a13[e]);
        *reinterpret_cast<uint4*>(&smem[yA * PITCHB + off]) = qa;
        const float b00[4] = {pB0[0].x, pB0[0].y, pB0[0].z, pB0[0].w};
        const float b01[4] = {pB0[1].x, pB0[1].y, pB0[1].z, pB0[1].w};
        const float b02[4] = {pB0[2].x, pB0[2].y, pB0[2].z, pB0[2].w};
        const float b03[4] = {pB0[3].x, pB0[3].y, pB0[3].z, pB0[3].w};
        const float b10[4] = {pB1[0].x, pB1[0].y, pB1[0].z, pB1[0].w};
        const float b11[4] = {pB1[1].x, pB1[1].y, pB1[1].z, pB1[1].w};
        const float b12[4] = {pB1[2].x, pB1[2].y, pB1[2].z, pB1[2].w};
        const float b13[4] = {pB1[3].x, pB1[3].y, pB1[3].z, pB1[3].w};
        uint4 qb;
        qb.x = cvt_pk_bf16(b00[e], b10[e]);
        qb.y = cvt_pk_bf16(b01[e], b11[e]);
        qb.z = cvt_pk_bf16(b02[e], b12[e]);
        qb.w = cvt_pk_bf16(b03[e], b13[e]);
        *reinterpret_cast<uint4*>(&smem[yB * PITCHB + off]) = qb;
    }
    __syncthreads();   // the ONLY barrier

    // MFMA decomposition.
    const int lane = tid & 63;
    const int wv   = tid >> 6;
    const int g    = lane >> 4;    // channel group (k) / oc block (C rows)
    const int m    = lane & 15;    // pixel within tile (C cols)
    const int rw   = wv >> 1;
    const int xq   = (wv & 1) * 64;

    int adr[4][3];
    #pragma unroll
    for (int t = 0; t < 4; ++t)
        #pragma unroll
        for (int dx = 0; dx < 3; ++dx) {
            int xi = xq + t * 16 + m + dx;
            int slot = (g ^ ((xi >> 1) ^ (xi >> 4))) & 3;
            adr[t][dx] = rw * PITCHB + xi * 64 + (slot << 4);
        }

    f32x4 acc[4][2];
    #pragma unroll
    for (int t = 0; t < 4; ++t)
        #pragma unroll
        for (int nt = 0; nt < 2; ++nt)
            acc[t][nt] = (f32x4){0.f, 0.f, 0.f, 0.f};

    #pragma unroll
    for (int kk = 0; kk < 9; ++kk) {
        const int dy = kk / 3, dxs = kk % 3;
        short8 b0 = *reinterpret_cast<const short8*>(bfrag + (((kk * 2 + 0) * 64 + lane) << 3));
        short8 b1 = *reinterpret_cast<const short8*>(bfrag + (((kk * 2 + 1) * 64 + lane) << 3));
        #pragma unroll
        for (int t = 0; t < 4; ++t) {
            short8 a = *reinterpret_cast<const short8*>(&smem[adr[t][dxs] + dy * PITCHB]);
            // swapped operands: C[row=oc][col=px]
            acc[t][0] = __builtin_amdgcn_mfma_f32_16x16x32_bf16(b0, a, acc[t][0], 0, 0, 0);
            acc[t][1] = __builtin_amdgcn_mfma_f32_16x16x32_bf16(b1, a, acc[t][1], 0, 0, 0);
        }
    }

    // Epilogue (fully in-register): BN shift + ReLU, head partials, butterfly.
    const float* hd = hdp + n * 144;
    const f32x4 shA = *reinterpret_cast<const f32x4*>(&shb[g * 4]);
    const f32x4 shB = *reinterpret_cast<const f32x4*>(&shb[16 + g * 4]);
    f32x4 w1A[4], w1B[4];
    #pragma unroll
    for (int o = 0; o < 4; ++o) {
        w1A[o] = *reinterpret_cast<const f32x4*>(&hd[o * 32 + g * 4]);
        w1B[o] = *reinterpret_cast<const f32x4*>(&hd[o * 32 + 16 + g * 4]);
    }

    float ph[4][4];   // [tile][o] partial head sums (this lane's 8 channels)
    #pragma unroll
    for (int t = 0; t < 4; ++t) {
        f32x4 vA, vB;
        vA.x = fmaxf(acc[t][0].x + shA.x, 0.f);
        vA.y = fmaxf(acc[t][0].y + shA.y, 0.f);
        vA.z = fmaxf(acc[t][0].z + shA.z, 0.f);
        vA.w = fmaxf(acc[t][0].w + shA.w, 0.f);
        vB.x = fmaxf(acc[t][1].x + shB.x, 0.f);
        vB.y = fmaxf(acc[t][1].y + shB.y, 0.f);
        vB.z = fmaxf(acc[t][1].z + shB.z, 0.f);
        vB.w = fmaxf(acc[t][1].w + shB.w, 0.f);
        #pragma unroll
        for (int o = 0; o < 4; ++o) {
            float p = vA.x * w1A[o].x;
            p = fmaf(vA.y, w1A[o].y, p);
            p = fmaf(vA.z, w1A[o].z, p);
            p = fmaf(vA.w, w1A[o].w, p);
            p = fmaf(vB.x, w1B[o].x, p);
            p = fmaf(vB.y, w1B[o].y, p);
            p = fmaf(vB.z, w1B[o].z, p);
            p = fmaf(vB.w, w1B[o].w, p);
            ph[t][o] = p;
        }
    }
    #pragma unroll
    for (int t = 0; t < 4; ++t)
        #pragma unroll
        for (int o = 0; o < 4; ++o) {
            float s = ph[t][o];
            s += __shfl_xor(s, 16);
            s += __shfl_xor(s, 32);
            ph[t][o] = s;
        }

    const f32x4 w2v = *reinterpret_cast<const f32x4*>(&hd[128]);
    const f32x4 b1v = *reinterpret_cast<const f32x4*>(&hd[132]);
    const float b2  = hd[136];
    float yv[4];
    #pragma unroll
    for (int t = 0; t < 4; ++t) {
        float q0 = fmaxf(ph[t][0] + b1v.x, 0.f);
        float q1 = fmaxf(ph[t][1] + b1v.y, 0.f);
        float q2 = fmaxf(ph[t][2] + b1v.z, 0.f);
        float q3 = fmaxf(ph[t][3] + b1v.w, 0.f);
        float yy = b2;
        yy = fmaf(w2v.x, q0, yy);
        yy = fmaf(w2v.y, q1, yy);
        yy = fmaf(w2v.z, q2, yy);
        yy = fmaf(w2v.w, q3, yy);
        yv[t] = yy;
    }
    // Lane stores pixel xq+lane using its own group's tile value.
    float ysel = (g == 0) ? yv[0] : (g == 1) ? yv[1] : (g == 2) ? yv[2] : yv[3];
    float s = 1.0f / (1.0f + __expf(-ysel));
    sig_out[(n << 14) + ((h0 + rw) << 7) + xq + lane] = s;
}

// ---- smooth: 5x5, 2ch -> 1ch ----
__global__ __launch_bounds__(256) void smooth_kernel(
    const float* __restrict__ sig,
    const float* __restrict__ masks,
    const float* __restrict__ sw,
    const float* __restrict__ sb,
    float* __restrict__ out)
{
    __shared__ float ls[2][400];

    const int tid  = threadIdx.x;
    const int n    = blockIdx.x >> 6;
    const int tile = blockIdx.x & 63;
    const int h0   = (tile >> 3) << 4;
    const int w0   = (tile & 7) << 4;

    for (int i = tid; i < 800; i += 256) {
        int chn = (i >= 400) ? 1 : 0;
        int r  = i - chn * 400;
        int yy = r / 20;
        int xx = r - yy * 20;
        int h  = h0 + yy - 2;
        int w  = w0 + xx - 2;
        float v = 0.0f;
        if ((unsigned)h < 128u && (unsigned)w < 128u) {
            const float* src = chn ? masks : sig;
            v = src[(n << 14) + (h << 7) + w];
        }
        ls[chn][r] = v;
    }
    __syncthreads();

    const int tx = tid & 15;
    const int ty = tid >> 4;

    float accv = sb[0];
    #pragma unroll
    for (int chn = 0; chn < 2; ++chn)
        #pragma unroll
        for (int dy = 0; dy < 5; ++dy)
            #pragma unroll
            for (int dx = 0; dx < 5; ++dx)
                accv = fmaf(ls[chn][(ty + dy) * 20 + tx + dx],
                            sw[(chn * 5 + dy) * 5 + dx], accv);
    out[(n << 14) + ((h0 + ty) << 7) + (w0 + tx)] = accv;
}

extern "C" void kernel_launch(void* const* d_in, const int* in_sizes, int n_in,
                              void* d_out, int out_size, void* d_ws, size_t ws_size,
                              hipStream_t stream) {
    const float* emb     = (const float*)d_in[0];
    const float* inc     = (const float*)d_in[1];
    const float* masks   = (const float*)d_in[2];
    const float* conv_w  = (const float*)d_in[3];
    const float* conv_b  = (const float*)d_in[4];
    const float* bn_g    = (const float*)d_in[5];
    const float* bn_b    = (const float*)d_in[6];
    const float* bn_m    = (const float*)d_in[7];
    const float* bn_v    = (const float*)d_in[8];
    const float* sw      = (const float*)d_in[9];
    const float* sb      = (const float*)d_in[10];
    float*  out   = (float*)d_out;
    float*  sig   = (float*)d_ws;
    ushort* bfrag = (ushort*)((char*)d_ws + BFRAG_OFF);
    float*  shb   = (float*)((char*)d_ws + SH_OFF);
    float*  hdp   = (float*)((char*)d_ws + HDP_OFF);

    prep_kernel<<<54, 256, 0, stream>>>(conv_w, conv_b, bn_g, bn_b, bn_m, bn_v,
                                        inc, bfrag, shb, hdp);
    fused_main_kernel<<<2048, 256, 0, stream>>>(emb, bfrag, shb, hdp, sig);
    smooth_kernel<<<2048, 256, 0, stream>>>(sig, masks, sw, sb, out);
}

// Round 8
// 35.822 us; speedup vs baseline: 1.0608x; 1.0219x over previous
//
#include <hip/hip_runtime.h>

// embedding: (32, 512, 32, 32) f32 ; pixel_shuffle r=4 -> x_ps (32, 32, 128, 128)
// conv 3x3 pad1 (32->32) + BN + ReLU ; head: 32->4 relu -> 1 ; sigmoid
// concat [sig, mask] -> 5x5 conv pad2 (2->1) ; out (32,1,128,128) f32
//
// v8: pipelined multi-band blocks with 6-row LDS ring buffer.
//     512 blocks x 4 bands (8 rows); per iteration: prefetch 2 NEW rows to
//     regs -> compute band (MFMA C[oc][px], in-reg head) -> ds_write rows ->
//     single barrier. Ring slots: reads {2it..2it+3}%6, writes {2it+4,+5}%6
//     (disjoint). Staging DS/HBM work halved vs v7; load latency hidden
//     under MFMA; head/BN params hoisted once per block.

typedef __attribute__((ext_vector_type(8))) short short8;
typedef __attribute__((ext_vector_type(4))) float f32x4;

static __device__ __forceinline__ ushort f2bf(float x) {
    union { float f; uint u; } v; v.f = x;
    uint r = v.u + 0x7fffu + ((v.u >> 16) & 1u);   // round-nearest-even
    return (ushort)(r >> 16);
}
static __device__ __forceinline__ uint cvt_pk_bf16(float lo, float hi) {
    uint r;
    asm("v_cvt_pk_bf16_f32 %0, %1, %2" : "=v"(r) : "v"(lo), "v"(hi));
    return r;   // {hi=bf16(hi), lo=bf16(lo)}
}

#define SIG_ELEMS (32 * 128 * 128)
#define BFRAG_OFF (SIG_ELEMS * 4)          // bytes into d_ws, 16B aligned
#define SH_OFF    (BFRAG_OFF + 18432)
#define HDP_OFF   (SH_OFF + 128)           // padded head params [32][144]

// ---- prep: pack B fragments (bf16, BN-scale folded) + shift + head repack ----
__global__ void prep_kernel(const float* __restrict__ conv_w,
                            const float* __restrict__ conv_b,
                            const float* __restrict__ bn_gamma,
                            const float* __restrict__ bn_beta,
                            const float* __restrict__ bn_mean,
                            const float* __restrict__ bn_var,
                            const float* __restrict__ inc,
                            ushort* __restrict__ bfrag,   // [18][64][8]
                            float* __restrict__ shb,      // [32]
                            float* __restrict__ hdp) {    // [32][144]
    int t = blockIdx.x * 256 + threadIdx.x;
    if (t < 9216) {
        int j    = t & 7;
        int lane = (t >> 3) & 63;
        int knt  = t >> 9;          // kk*2 + nt
        int kk   = knt >> 1;
        int nt   = knt & 1;
        int oc   = (lane & 15) + nt * 16;
        int c    = (lane >> 4) * 8 + j;
        float sc = bn_gamma[oc] * rsqrtf(bn_var[oc] + 1e-5f);
        bfrag[t] = f2bf(conv_w[oc * 288 + c * 9 + kk] * sc);
    } else if (t < 9248) {
        int oc = t - 9216;
        float sc = bn_gamma[oc] * rsqrtf(bn_var[oc] + 1e-5f);
        shb[oc] = (conv_b[oc] - bn_mean[oc]) * sc + bn_beta[oc];
    } else if (t < 9248 + 32 * 137) {
        int i = t - 9248;
        int nn = i / 137, r = i - nn * 137;
        hdp[nn * 144 + r] = inc[i];
    }
}

// ---- main: pipelined implicit-GEMM conv + BN + ReLU + head + sigmoid ----
#define PITCHB 8320          // 130 cells * 64 B per staged row
#define NRING  6

__global__ __launch_bounds__(256, 2) void fused_main_kernel(
    const float* __restrict__ emb,      // (32,512,32,32)
    const ushort* __restrict__ bfrag,   // [18][64][8] bf16 (scale-folded)
    const float* __restrict__ shb,      // [32]
    const float* __restrict__ hdp,      // [32][144]
    float* __restrict__ sig_out)        // (32,128,128)
{
    __shared__ __align__(16) char smem[NRING * PITCHB];   // 49920 B

    const int bid = blockIdx.x;
    const int lid = (bid & 7) * 64 + (bid >> 3);   // XCD swizzle (512 = 8*64)
    const int n   = lid >> 4;     // image 0..31
    const int q   = lid & 15;     // 8-row chunk 0..15
    const int hq0 = q << 3;       // first output row

    const int tid  = threadIdx.x;

    // Staging decomposition: (f, cphi, sx, yy)
    const int f    = tid & 7;
    const int cphi = (tid >> 3) & 3;
    const int sx   = (tid >> 5) & 3;
    const int yy   = tid >> 7;         // 0/1

    // ---- prologue: stage ring rows 0..3 = image rows hq0-1 .. hq0+2 ----
    {
        const int rA = yy, rB = yy + 2;
        const int hA = hq0 + rA - 1, hB = hq0 + rB - 1;
        const bool vA = (unsigned)hA < 128u;
        const bool vB = (unsigned)hB < 128u;
        float4 pA0[4], pA1[4], pB0[4], pB1[4];
        #pragma unroll
        for (int cplo = 0; cplo < 4; ++cplo) {
            pA0[cplo] = make_float4(0.f, 0.f, 0.f, 0.f);
            pA1[cplo] = pA0[cplo]; pB0[cplo] = pA0[cplo]; pB1[cplo] = pA0[cplo];
            if (vA) {
                int cc = cphi * 128 + cplo * 32 + ((hA & 3) << 2) + sx;
                long base = ((long)(n * 512 + cc) << 10) + ((hA >> 2) << 5) + (f << 2);
                pA0[cplo] = *reinterpret_cast<const float4*>(&emb[base]);
                pA1[cplo] = *reinterpret_cast<const float4*>(&emb[base + (16 << 10)]);
            }
            if (vB) {
                int cc = cphi * 128 + cplo * 32 + ((hB & 3) << 2) + sx;
                long base = ((long)(n * 512 + cc) << 10) + ((hB >> 2) << 5) + (f << 2);
                pB0[cplo] = *reinterpret_cast<const float4*>(&emb[base]);
                pB1[cplo] = *reinterpret_cast<const float4*>(&emb[base + (16 << 10)]);
            }
        }
        __builtin_amdgcn_sched_barrier(0);
        // halo-zero columns xi=0,129 for all 6 ring rows (overlaps load latency)
        if (tid < 192) {
            int cell = tid >> 4;       // 0..11
            int wrd  = tid & 15;
            int row  = cell >> 1;
            int col  = (cell & 1) ? 129 : 0;
            ((uint*)smem)[(row * PITCHB + col * 64) / 4 + wrd] = 0u;
        }
        const float a00[4] = {pA0[0].x, pA0[0].y, pA0[0].z, pA0[0].w};
        const float a01[4] = {pA0[1].x, pA0[1].y, pA0[1].z, pA0[1].w};
        const float a02[4] = {pA0[2].x, pA0[2].y, pA0[2].z, pA0[2].w};
        const float a03[4] = {pA0[3].x, pA0[3].y, pA0[3].z, pA0[3].w};
        const float a10[4] = {pA1[0].x, pA1[0].y, pA1[0].z, pA1[0].w};
        const float a11[4] = {pA1[1].x, pA1[1].y, pA1[1].z, pA1[1].w};
        const float a12[4] = {pA1[2].x, pA1[2].y, pA1[2].z, pA1[2].w};
        const float a13[4] = {pA1[3].x, pA1[3].y, pA1[3].z, pA1[3].w};
        const float b00[4] = {pB0[0].x, pB0[0].y, pB0[0].z, pB0[0].w};
        const float b01[4] = {pB0[1].x, pB0[1].y, pB0[1].z, pB0[1].w};
        const float b02[4] = {pB0[2].x, pB0[2].y, pB0[2].z, pB0[2].w};
        const float b03[4] = {pB0[3].x, pB0[3].y, pB0[3].z, pB0[3].w};
        const float b10[4] = {pB1[0].x, pB1[0].y, pB1[0].z, pB1[0].w};
        const float b11[4] = {pB1[1].x, pB1[1].y, pB1[1].z, pB1[1].w};
        const float b12[4] = {pB1[2].x, pB1[2].y, pB1[2].z, pB1[2].w};
        const float b13[4] = {pB1[3].x, pB1[3].y, pB1[3].z, pB1[3].w};
        #pragma unroll
        for (int e = 0; e < 4; ++e) {
            int xi   = 1 + sx + (f << 4) + (e << 2);
            int slot = (cphi ^ ((xi >> 1) ^ (xi >> 4))) & 3;
            int off  = xi * 64 + (slot << 4);
            uint4 qa;
            qa.x = cvt_pk_bf16(a00[e], a10[e]);
            qa.y = cvt_pk_bf16(a01[e], a11[e]);
            qa.z = cvt_pk_bf16(a02[e], a12[e]);
            qa.w = cvt_pk_bf16(a03[e], a13[e]);
            *reinterpret_cast<uint4*>(&smem[rA * PITCHB + off]) = qa;
            uint4 qb;
            qb.x = cvt_pk_bf16(b00[e], b10[e]);
            qb.y = cvt_pk_bf16(b01[e], b11[e]);
            qb.z = cvt_pk_bf16(b02[e], b12[e]);
            qb.w = cvt_pk_bf16(b03[e], b13[e]);
            *reinterpret_cast<uint4*>(&smem[rB * PITCHB + off]) = qb;
        }
    }

    // MFMA-side constants (loop-invariant).
    const int lane = tid & 63;
    const int wv   = tid >> 6;
    const int g    = lane >> 4;    // channel group / oc block
    const int m    = lane & 15;    // pixel col within tile
    const int rw   = wv >> 1;      // wave's row within band
    const int xq   = (wv & 1) * 64;

    int cell_off[4][3];
    #pragma unroll
    for (int t = 0; t < 4; ++t)
        #pragma unroll
        for (int dx = 0; dx < 3; ++dx) {
            int xi = xq + t * 16 + m + dx;
            int slot = (g ^ ((xi >> 1) ^ (xi >> 4))) & 3;
            cell_off[t][dx] = xi * 64 + (slot << 4);
        }

    // Hoisted head/BN params.
    const float* hd = hdp + n * 144;
    const f32x4 shA = *reinterpret_cast<const f32x4*>(&shb[g * 4]);
    const f32x4 shB = *reinterpret_cast<const f32x4*>(&shb[16 + g * 4]);
    f32x4 w1A[4], w1B[4];
    #pragma unroll
    for (int o = 0; o < 4; ++o) {
        w1A[o] = *reinterpret_cast<const f32x4*>(&hd[o * 32 + g * 4]);
        w1B[o] = *reinterpret_cast<const f32x4*>(&hd[o * 32 + 16 + g * 4]);
    }
    const f32x4 w2v = *reinterpret_cast<const f32x4*>(&hd[128]);
    const f32x4 b1v = *reinterpret_cast<const f32x4*>(&hd[132]);
    const float b2  = hd[136];

    __syncthreads();

    #pragma unroll 1
    for (int it = 0; it < 4; ++it) {
        // ---- phase A: prefetch the 2 NEW rows for band it+1 ----
        float4 np0[4], np1[4];
        const bool have = (it < 3);
        const int  hn   = hq0 + 2 * it + 3 + yy;
        const bool vn   = have && (hn < 128);
        #pragma unroll
        for (int cplo = 0; cplo < 4; ++cplo) {
            np0[cplo] = make_float4(0.f, 0.f, 0.f, 0.f);
            np1[cplo] = np0[cplo];
            if (vn) {
                int cc = cphi * 128 + cplo * 32 + ((hn & 3) << 2) + sx;
                long base = ((long)(n * 512 + cc) << 10) + ((hn >> 2) << 5) + (f << 2);
                np0[cplo] = *reinterpret_cast<const float4*>(&emb[base]);
                np1[cplo] = *reinterpret_cast<const float4*>(&emb[base + (16 << 10)]);
            }
        }
        __builtin_amdgcn_sched_barrier(0);   // pin loads before compute

        // ---- phase B: compute band it ----
        int rb[3];
        #pragma unroll
        for (int dy = 0; dy < 3; ++dy) {
            int r = 2 * it + rw + dy;
            if (r >= NRING) r -= NRING;
            rb[dy] = r * PITCHB;
        }

        f32x4 acc[4][2];
        #pragma unroll
        for (int t = 0; t < 4; ++t)
            #pragma unroll
            for (int nt = 0; nt < 2; ++nt)
                acc[t][nt] = (f32x4){0.f, 0.f, 0.f, 0.f};

        #pragma unroll
        for (int kk = 0; kk < 9; ++kk) {
            const int dy = kk / 3, dxs = kk % 3;
            short8 b0 = *reinterpret_cast<const short8*>(bfrag + (((kk * 2 + 0) * 64 + lane) << 3));
            short8 b1 = *reinterpret_cast<const short8*>(bfrag + (((kk * 2 + 1) * 64 + lane) << 3));
            #pragma unroll
            for (int t = 0; t < 4; ++t) {
                short8 a = *reinterpret_cast<const short8*>(&smem[rb[dy] + cell_off[t][dxs]]);
                acc[t][0] = __builtin_amdgcn_mfma_f32_16x16x32_bf16(b0, a, acc[t][0], 0, 0, 0);
                acc[t][1] = __builtin_amdgcn_mfma_f32_16x16x32_bf16(b1, a, acc[t][1], 0, 0, 0);
            }
        }

        // Epilogue: BN shift + ReLU, head partials, butterfly, sigmoid, store.
        float ph[4][4];
        #pragma unroll
        for (int t = 0; t < 4; ++t) {
            f32x4 vA, vB;
            vA.x = fmaxf(acc[t][0].x + shA.x, 0.f);
            vA.y = fmaxf(acc[t][0].y + shA.y, 0.f);
            vA.z = fmaxf(acc[t][0].z + shA.z, 0.f);
            vA.w = fmaxf(acc[t][0].w + shA.w, 0.f);
            vB.x = fmaxf(acc[t][1].x + shB.x, 0.f);
            vB.y = fmaxf(acc[t][1].y + shB.y, 0.f);
            vB.z = fmaxf(acc[t][1].z + shB.z, 0.f);
            vB.w = fmaxf(acc[t][1].w + shB.w, 0.f);
            #pragma unroll
            for (int o = 0; o < 4; ++o) {
                float p = vA.x * w1A[o].x;
                p = fmaf(vA.y, w1A[o].y, p);
                p = fmaf(vA.z, w1A[o].z, p);
                p = fmaf(vA.w, w1A[o].w, p);
                p = fmaf(vB.x, w1B[o].x, p);
                p = fmaf(vB.y, w1B[o].y, p);
                p = fmaf(vB.z, w1B[o].z, p);
                p = fmaf(vB.w, w1B[o].w, p);
                ph[t][o] = p;
            }
        }
        #pragma unroll
        for (int t = 0; t < 4; ++t)
            #pragma unroll
            for (int o = 0; o < 4; ++o) {
                float s = ph[t][o];
                s += __shfl_xor(s, 16);
                s += __shfl_xor(s, 32);
                ph[t][o] = s;
            }
        float yv[4];
        #pragma unroll
        for (int t = 0; t < 4; ++t) {
            float q0 = fmaxf(ph[t][0] + b1v.x, 0.f);
            float q1 = fmaxf(ph[t][1] + b1v.y, 0.f);
            float q2 = fmaxf(ph[t][2] + b1v.z, 0.f);
            float q3 = fmaxf(ph[t][3] + b1v.w, 0.f);
            float yyv = b2;
            yyv = fmaf(w2v.x, q0, yyv);
            yyv = fmaf(w2v.y, q1, yyv);
            yyv = fmaf(w2v.z, q2, yyv);
            yyv = fmaf(w2v.w, q3, yyv);
            yv[t] = yyv;
        }
        float ysel = (g == 0) ? yv[0] : (g == 1) ? yv[1] : (g == 2) ? yv[2] : yv[3];
        float sv = 1.0f / (1.0f + __expf(-ysel));
        sig_out[(n << 14) + ((hq0 + 2 * it + rw) << 7) + xq + lane] = sv;

        // ---- phase C: write the prefetched rows into ring slots ----
        if (have) {
            int rs = 2 * it + 4 + yy;
            if (rs >= NRING) rs -= NRING;
            const float c00[4] = {np0[0].x, np0[0].y, np0[0].z, np0[0].w};
            const float c01[4] = {np0[1].x, np0[1].y, np0[1].z, np0[1].w};
            const float c02[4] = {np0[2].x, np0[2].y, np0[2].z, np0[2].w};
            const float c03[4] = {np0[3].x, np0[3].y, np0[3].z, np0[3].w};
            const float c10[4] = {np1[0].x, np1[0].y, np1[0].z, np1[0].w};
            const float c11[4] = {np1[1].x, np1[1].y, np1[1].z, np1[1].w};
            const float c12[4] = {np1[2].x, np1[2].y, np1[2].z, np1[2].w};
            const float c13[4] = {np1[3].x, np1[3].y, np1[3].z, np1[3].w};
            #pragma unroll
            for (int e = 0; e < 4; ++e) {
                int xi   = 1 + sx + (f << 4) + (e << 2);
                int slot = (cphi ^ ((xi >> 1) ^ (xi >> 4))) & 3;
                uint4 qv;
                qv.x = cvt_pk_bf16(c00[e], c10[e]);
                qv.y = cvt_pk_bf16(c01[e], c11[e]);
                qv.z = cvt_pk_bf16(c02[e], c12[e]);
                qv.w = cvt_pk_bf16(c03[e], c13[e]);
                *reinterpret_cast<uint4*>(&smem[rs * PITCHB + xi * 64 + (slot << 4)]) = qv;
            }
        }
        __syncthreads();
    }
}

// ---- smooth: 5x5, 2ch -> 1ch ----
__global__ __launch_bounds__(256) void smooth_kernel(
    const float* __restrict__ sig,
    const float* __restrict__ masks,
    const float* __restrict__ sw,
    const float* __restrict__ sb,
    float* __restrict__ out)
{
    __shared__ float ls[2][400];

    const int tid  = threadIdx.x;
    const int n    = blockIdx.x >> 6;
    const int tile = blockIdx.x & 63;
    const int h0   = (tile >> 3) << 4;
    const int w0   = (tile & 7) << 4;

    for (int i = tid; i < 800; i += 256) {
        int chn = (i >= 400) ? 1 : 0;
        int r  = i - chn * 400;
        int yy = r / 20;
        int xx = r - yy * 20;
        int h  = h0 + yy - 2;
        int w  = w0 + xx - 2;
        float v = 0.0f;
        if ((unsigned)h < 128u && (unsigned)w < 128u) {
            const float* src = chn ? masks : sig;
            v = src[(n << 14) + (h << 7) + w];
        }
        ls[chn][r] = v;
    }
    __syncthreads();

    const int tx = tid & 15;
    const int ty = tid >> 4;

    float accv = sb[0];
    #pragma unroll
    for (int chn = 0; chn < 2; ++chn)
        #pragma unroll
        for (int dy = 0; dy < 5; ++dy)
            #pragma unroll
            for (int dx = 0; dx < 5; ++dx)
                accv = fmaf(ls[chn][(ty + dy) * 20 + tx + dx],
                            sw[(chn * 5 + dy) * 5 + dx], accv);
    out[(n << 14) + ((h0 + ty) << 7) + (w0 + tx)] = accv;
}

extern "C" void kernel_launch(void* const* d_in, const int* in_sizes, int n_in,
                              void* d_out, int out_size, void* d_ws, size_t ws_size,
                              hipStream_t stream) {
    const float* emb     = (const float*)d_in[0];
    const float* inc     = (const float*)d_in[1];
    const float* masks   = (const float*)d_in[2];
    const float* conv_w  = (const float*)d_in[3];
    const float* conv_b  = (const float*)d_in[4];
    const float* bn_g    = (const float*)d_in[5];
    const float* bn_b    = (const float*)d_in[6];
    const float* bn_m    = (const float*)d_in[7];
    const float* bn_v    = (const float*)d_in[8];
    const float* sw      = (const float*)d_in[9];
    const float* sb      = (const float*)d_in[10];
    float*  out   = (float*)d_out;
    float*  sig   = (float*)d_ws;
    ushort* bfrag = (ushort*)((char*)d_ws + BFRAG_OFF);
    float*  shb   = (float*)((char*)d_ws + SH_OFF);
    float*  hdp   = (float*)((char*)d_ws + HDP_OFF);

    prep_kernel<<<54, 256, 0, stream>>>(conv_w, conv_b, bn_g, bn_b, bn_m, bn_v,
                                        inc, bfrag, shb, hdp);
    fused_main_kernel<<<512, 256, 0, stream>>>(emb, bfrag, shb, hdp, sig);
    smooth_kernel<<<2048, 256, 0, stream>>>(sig, masks, sw, sb, out);
}

// Round 9
// 33.905 us; speedup vs baseline: 1.1207x; 1.0565x over previous
//
#include <hip/hip_runtime.h>

// embedding: (32, 512, 32, 32) f32 ; pixel_shuffle r=4 -> x_ps (32, 32, 128, 128)
// conv 3x3 pad1 (32->32) + BN + ReLU ; head: 32->4 relu -> 1 ; sigmoid
// concat [sig, mask] -> 5x5 conv pad2 (2->1) ; out (32,1,128,128) f32
//
// v9: v8 ring pipeline + (a) bfrag hoisted to 72 VGPRs once per block
//     (kk-loop becomes pure ds_read+MFMA, -72 VMEM/wave/block),
//     (b) s_setprio(1) around the MFMA cluster (T5; de-phased blocks).

typedef __attribute__((ext_vector_type(8))) short short8;
typedef __attribute__((ext_vector_type(4))) float f32x4;

static __device__ __forceinline__ ushort f2bf(float x) {
    union { float f; uint u; } v; v.f = x;
    uint r = v.u + 0x7fffu + ((v.u >> 16) & 1u);   // round-nearest-even
    return (ushort)(r >> 16);
}
static __device__ __forceinline__ uint cvt_pk_bf16(float lo, float hi) {
    uint r;
    asm("v_cvt_pk_bf16_f32 %0, %1, %2" : "=v"(r) : "v"(lo), "v"(hi));
    return r;   // {hi=bf16(hi), lo=bf16(lo)}
}

#define SIG_ELEMS (32 * 128 * 128)
#define BFRAG_OFF (SIG_ELEMS * 4)          // bytes into d_ws, 16B aligned
#define SH_OFF    (BFRAG_OFF + 18432)
#define HDP_OFF   (SH_OFF + 128)           // padded head params [32][144]

// ---- prep: pack B fragments (bf16, BN-scale folded) + shift + head repack ----
__global__ void prep_kernel(const float* __restrict__ conv_w,
                            const float* __restrict__ conv_b,
                            const float* __restrict__ bn_gamma,
                            const float* __restrict__ bn_beta,
                            const float* __restrict__ bn_mean,
                            const float* __restrict__ bn_var,
                            const float* __restrict__ inc,
                            ushort* __restrict__ bfrag,   // [18][64][8]
                            float* __restrict__ shb,      // [32]
                            float* __restrict__ hdp) {    // [32][144]
    int t = blockIdx.x * 256 + threadIdx.x;
    if (t < 9216) {
        int j    = t & 7;
        int lane = (t >> 3) & 63;
        int knt  = t >> 9;          // kk*2 + nt
        int kk   = knt >> 1;
        int nt   = knt & 1;
        int oc   = (lane & 15) + nt * 16;
        int c    = (lane >> 4) * 8 + j;
        float sc = bn_gamma[oc] * rsqrtf(bn_var[oc] + 1e-5f);
        bfrag[t] = f2bf(conv_w[oc * 288 + c * 9 + kk] * sc);
    } else if (t < 9248) {
        int oc = t - 9216;
        float sc = bn_gamma[oc] * rsqrtf(bn_var[oc] + 1e-5f);
        shb[oc] = (conv_b[oc] - bn_mean[oc]) * sc + bn_beta[oc];
    } else if (t < 9248 + 32 * 137) {
        int i = t - 9248;
        int nn = i / 137, r = i - nn * 137;
        hdp[nn * 144 + r] = inc[i];
    }
}

// ---- main: pipelined implicit-GEMM conv + BN + ReLU + head + sigmoid ----
#define PITCHB 8320          // 130 cells * 64 B per staged row
#define NRING  6

__global__ __launch_bounds__(256, 2) void fused_main_kernel(
    const float* __restrict__ emb,      // (32,512,32,32)
    const ushort* __restrict__ bfrag,   // [18][64][8] bf16 (scale-folded)
    const float* __restrict__ shb,      // [32]
    const float* __restrict__ hdp,      // [32][144]
    float* __restrict__ sig_out)        // (32,128,128)
{
    __shared__ __align__(16) char smem[NRING * PITCHB];   // 49920 B

    const int bid = blockIdx.x;
    const int lid = (bid & 7) * 64 + (bid >> 3);   // XCD swizzle (512 = 8*64)
    const int n   = lid >> 4;     // image 0..31
    const int q   = lid & 15;     // 8-row chunk 0..15
    const int hq0 = q << 3;       // first output row

    const int tid  = threadIdx.x;

    // Staging decomposition: (f, cphi, sx, yy)
    const int f    = tid & 7;
    const int cphi = (tid >> 3) & 3;
    const int sx   = (tid >> 5) & 3;
    const int yy   = tid >> 7;         // 0/1

    // ---- prologue: stage ring rows 0..3 = image rows hq0-1 .. hq0+2 ----
    {
        const int rA = yy, rB = yy + 2;
        const int hA = hq0 + rA - 1, hB = hq0 + rB - 1;
        const bool vA = (unsigned)hA < 128u;
        const bool vB = (unsigned)hB < 128u;
        float4 pA0[4], pA1[4], pB0[4], pB1[4];
        #pragma unroll
        for (int cplo = 0; cplo < 4; ++cplo) {
            pA0[cplo] = make_float4(0.f, 0.f, 0.f, 0.f);
            pA1[cplo] = pA0[cplo]; pB0[cplo] = pA0[cplo]; pB1[cplo] = pA0[cplo];
            if (vA) {
                int cc = cphi * 128 + cplo * 32 + ((hA & 3) << 2) + sx;
                long base = ((long)(n * 512 + cc) << 10) + ((hA >> 2) << 5) + (f << 2);
                pA0[cplo] = *reinterpret_cast<const float4*>(&emb[base]);
                pA1[cplo] = *reinterpret_cast<const float4*>(&emb[base + (16 << 10)]);
            }
            if (vB) {
                int cc = cphi * 128 + cplo * 32 + ((hB & 3) << 2) + sx;
                long base = ((long)(n * 512 + cc) << 10) + ((hB >> 2) << 5) + (f << 2);
                pB0[cplo] = *reinterpret_cast<const float4*>(&emb[base]);
                pB1[cplo] = *reinterpret_cast<const float4*>(&emb[base + (16 << 10)]);
            }
        }
        __builtin_amdgcn_sched_barrier(0);
        // halo-zero columns xi=0,129 for all 6 ring rows (overlaps load latency)
        if (tid < 192) {
            int cell = tid >> 4;       // 0..11
            int wrd  = tid & 15;
            int row  = cell >> 1;
            int col  = (cell & 1) ? 129 : 0;
            ((uint*)smem)[(row * PITCHB + col * 64) / 4 + wrd] = 0u;
        }
        const float a00[4] = {pA0[0].x, pA0[0].y, pA0[0].z, pA0[0].w};
        const float a01[4] = {pA0[1].x, pA0[1].y, pA0[1].z, pA0[1].w};
        const float a02[4] = {pA0[2].x, pA0[2].y, pA0[2].z, pA0[2].w};
        const float a03[4] = {pA0[3].x, pA0[3].y, pA0[3].z, pA0[3].w};
        const float a10[4] = {pA1[0].x, pA1[0].y, pA1[0].z, pA1[0].w};
        const float a11[4] = {pA1[1].x, pA1[1].y, pA1[1].z, pA1[1].w};
        const float a12[4] = {pA1[2].x, pA1[2].y, pA1[2].z, pA1[2].w};
        const float a13[4] = {pA1[3].x, pA1[3].y, pA1[3].z, pA1[3].w};
        const float b00[4] = {pB0[0].x, pB0[0].y, pB0[0].z, pB0[0].w};
        const float b01[4] = {pB0[1].x, pB0[1].y, pB0[1].z, pB0[1].w};
        const float b02[4] = {pB0[2].x, pB0[2].y, pB0[2].z, pB0[2].w};
        const float b03[4] = {pB0[3].x, pB0[3].y, pB0[3].z, pB0[3].w};
        const float b10[4] = {pB1[0].x, pB1[0].y, pB1[0].z, pB1[0].w};
        const float b11[4] = {pB1[1].x, pB1[1].y, pB1[1].z, pB1[1].w};
        const float b12[4] = {pB1[2].x, pB1[2].y, pB1[2].z, pB1[2].w};
        const float b13[4] = {pB1[3].x, pB1[3].y, pB1[3].z, pB1[3].w};
        #pragma unroll
        for (int e = 0; e < 4; ++e) {
            int xi   = 1 + sx + (f << 4) + (e << 2);
            int slot = (cphi ^ ((xi >> 1) ^ (xi >> 4))) & 3;
            int off  = xi * 64 + (slot << 4);
            uint4 qa;
            qa.x = cvt_pk_bf16(a00[e], a10[e]);
            qa.y = cvt_pk_bf16(a01[e], a11[e]);
            qa.z = cvt_pk_bf16(a02[e], a12[e]);
            qa.w = cvt_pk_bf16(a03[e], a13[e]);
            *reinterpret_cast<uint4*>(&smem[rA * PITCHB + off]) = qa;
            uint4 qb;
            qb.x = cvt_pk_bf16(b00[e], b10[e]);
            qb.y = cvt_pk_bf16(b01[e], b11[e]);
            qb.z = cvt_pk_bf16(b02[e], b12[e]);
            qb.w = cvt_pk_bf16(b03[e], b13[e]);
            *reinterpret_cast<uint4*>(&smem[rB * PITCHB + off]) = qb;
        }
    }

    // MFMA-side constants (loop-invariant).
    const int lane = tid & 63;
    const int wv   = tid >> 6;
    const int g    = lane >> 4;    // channel group / oc block
    const int m    = lane & 15;    // pixel col within tile
    const int rw   = wv >> 1;      // wave's row within band
    const int xq   = (wv & 1) * 64;

    int cell_off[4][3];
    #pragma unroll
    for (int t = 0; t < 4; ++t)
        #pragma unroll
        for (int dx = 0; dx < 3; ++dx) {
            int xi = xq + t * 16 + m + dx;
            int slot = (g ^ ((xi >> 1) ^ (xi >> 4))) & 3;
            cell_off[t][dx] = xi * 64 + (slot << 4);
        }

    // Hoisted B fragments: 18 x short8 = 72 VGPRs, loaded ONCE per block.
    short8 bf0[9], bf1[9];
    #pragma unroll
    for (int kk = 0; kk < 9; ++kk) {
        bf0[kk] = *reinterpret_cast<const short8*>(bfrag + (((kk * 2 + 0) * 64 + lane) << 3));
        bf1[kk] = *reinterpret_cast<const short8*>(bfrag + (((kk * 2 + 1) * 64 + lane) << 3));
    }

    // Hoisted head/BN params.
    const float* hd = hdp + n * 144;
    const f32x4 shA = *reinterpret_cast<const f32x4*>(&shb[g * 4]);
    const f32x4 shB = *reinterpret_cast<const f32x4*>(&shb[16 + g * 4]);
    f32x4 w1A[4], w1B[4];
    #pragma unroll
    for (int o = 0; o < 4; ++o) {
        w1A[o] = *reinterpret_cast<const f32x4*>(&hd[o * 32 + g * 4]);
        w1B[o] = *reinterpret_cast<const f32x4*>(&hd[o * 32 + 16 + g * 4]);
    }
    const f32x4 w2v = *reinterpret_cast<const f32x4*>(&hd[128]);
    const f32x4 b1v = *reinterpret_cast<const f32x4*>(&hd[132]);
    const float b2  = hd[136];

    __syncthreads();

    #pragma unroll 1
    for (int it = 0; it < 4; ++it) {
        // ---- phase A: prefetch the 2 NEW rows for band it+1 ----
        float4 np0[4], np1[4];
        const bool have = (it < 3);
        const int  hn   = hq0 + 2 * it + 3 + yy;
        const bool vn   = have && (hn < 128);
        #pragma unroll
        for (int cplo = 0; cplo < 4; ++cplo) {
            np0[cplo] = make_float4(0.f, 0.f, 0.f, 0.f);
            np1[cplo] = np0[cplo];
            if (vn) {
                int cc = cphi * 128 + cplo * 32 + ((hn & 3) << 2) + sx;
                long base = ((long)(n * 512 + cc) << 10) + ((hn >> 2) << 5) + (f << 2);
                np0[cplo] = *reinterpret_cast<const float4*>(&emb[base]);
                np1[cplo] = *reinterpret_cast<const float4*>(&emb[base + (16 << 10)]);
            }
        }
        __builtin_amdgcn_sched_barrier(0);   // pin loads before compute

        // ---- phase B: compute band it ----
        int rb[3];
        #pragma unroll
        for (int dy = 0; dy < 3; ++dy) {
            int r = 2 * it + rw + dy;
            if (r >= NRING) r -= NRING;
            rb[dy] = r * PITCHB;
        }

        f32x4 acc[4][2];
        #pragma unroll
        for (int t = 0; t < 4; ++t)
            #pragma unroll
            for (int nt = 0; nt < 2; ++nt)
                acc[t][nt] = (f32x4){0.f, 0.f, 0.f, 0.f};

        __builtin_amdgcn_s_setprio(1);
        #pragma unroll
        for (int kk = 0; kk < 9; ++kk) {
            const int dy = kk / 3, dxs = kk % 3;
            #pragma unroll
            for (int t = 0; t < 4; ++t) {
                short8 a = *reinterpret_cast<const short8*>(&smem[rb[dy] + cell_off[t][dxs]]);
                acc[t][0] = __builtin_amdgcn_mfma_f32_16x16x32_bf16(bf0[kk], a, acc[t][0], 0, 0, 0);
                acc[t][1] = __builtin_amdgcn_mfma_f32_16x16x32_bf16(bf1[kk], a, acc[t][1], 0, 0, 0);
            }
        }
        __builtin_amdgcn_s_setprio(0);

        // Epilogue: BN shift + ReLU, head partials, butterfly, sigmoid, store.
        float ph[4][4];
        #pragma unroll
        for (int t = 0; t < 4; ++t) {
            f32x4 vA, vB;
            vA.x = fmaxf(acc[t][0].x + shA.x, 0.f);
            vA.y = fmaxf(acc[t][0].y + shA.y, 0.f);
            vA.z = fmaxf(acc[t][0].z + shA.z, 0.f);
            vA.w = fmaxf(acc[t][0].w + shA.w, 0.f);
            vB.x = fmaxf(acc[t][1].x + shB.x, 0.f);
            vB.y = fmaxf(acc[t][1].y + shB.y, 0.f);
            vB.z = fmaxf(acc[t][1].z + shB.z, 0.f);
            vB.w = fmaxf(acc[t][1].w + shB.w, 0.f);
            #pragma unroll
            for (int o = 0; o < 4; ++o) {
                float p = vA.x * w1A[o].x;
                p = fmaf(vA.y, w1A[o].y, p);
                p = fmaf(vA.z, w1A[o].z, p);
                p = fmaf(vA.w, w1A[o].w, p);
                p = fmaf(vB.x, w1B[o].x, p);
                p = fmaf(vB.y, w1B[o].y, p);
                p = fmaf(vB.z, w1B[o].z, p);
                p = fmaf(vB.w, w1B[o].w, p);
                ph[t][o] = p;
            }
        }
        #pragma unroll
        for (int t = 0; t < 4; ++t)
            #pragma unroll
            for (int o = 0; o < 4; ++o) {
                float s = ph[t][o];
                s += __shfl_xor(s, 16);
                s += __shfl_xor(s, 32);
                ph[t][o] = s;
            }
        float yv[4];
        #pragma unroll
        for (int t = 0; t < 4; ++t) {
            float q0 = fmaxf(ph[t][0] + b1v.x, 0.f);
            float q1 = fmaxf(ph[t][1] + b1v.y, 0.f);
            float q2 = fmaxf(ph[t][2] + b1v.z, 0.f);
            float q3 = fmaxf(ph[t][3] + b1v.w, 0.f);
            float yyv = b2;
            yyv = fmaf(w2v.x, q0, yyv);
            yyv = fmaf(w2v.y, q1, yyv);
            yyv = fmaf(w2v.z, q2, yyv);
            yyv = fmaf(w2v.w, q3, yyv);
            yv[t] = yyv;
        }
        float ysel = (g == 0) ? yv[0] : (g == 1) ? yv[1] : (g == 2) ? yv[2] : yv[3];
        float sv = 1.0f / (1.0f + __expf(-ysel));
        sig_out[(n << 14) + ((hq0 + 2 * it + rw) << 7) + xq + lane] = sv;

        // ---- phase C: write the prefetched rows into ring slots ----
        if (have) {
            int rs = 2 * it + 4 + yy;
            if (rs >= NRING) rs -= NRING;
            const float c00[4] = {np0[0].x, np0[0].y, np0[0].z, np0[0].w};
            const float c01[4] = {np0[1].x, np0[1].y, np0[1].z, np0[1].w};
            const float c02[4] = {np0[2].x, np0[2].y, np0[2].z, np0[2].w};
            const float c03[4] = {np0[3].x, np0[3].y, np0[3].z, np0[3].w};
            const float c10[4] = {np1[0].x, np1[0].y, np1[0].z, np1[0].w};
            const float c11[4] = {np1[1].x, np1[1].y, np1[1].z, np1[1].w};
            const float c12[4] = {np1[2].x, np1[2].y, np1[2].z, np1[2].w};
            const float c13[4] = {np1[3].x, np1[3].y, np1[3].z, np1[3].w};
            #pragma unroll
            for (int e = 0; e < 4; ++e) {
                int xi   = 1 + sx + (f << 4) + (e << 2);
                int slot = (cphi ^ ((xi >> 1) ^ (xi >> 4))) & 3;
                uint4 qv;
                qv.x = cvt_pk_bf16(c00[e], c10[e]);
                qv.y = cvt_pk_bf16(c01[e], c11[e]);
                qv.z = cvt_pk_bf16(c02[e], c12[e]);
                qv.w = cvt_pk_bf16(c03[e], c13[e]);
                *reinterpret_cast<uint4*>(&smem[rs * PITCHB + xi * 64 + (slot << 4)]) = qv;
            }
        }
        __syncthreads();
    }
}

// ---- smooth: 5x5, 2ch -> 1ch ----
__global__ __launch_bounds__(256) void smooth_kernel(
    const float* __restrict__ sig,
    const float* __restrict__ masks,
    const float* __restrict__ sw,
    const float* __restrict__ sb,
    float* __restrict__ out)
{
    __shared__ float ls[2][400];

    const int tid  = threadIdx.x;
    const int n    = blockIdx.x >> 6;
    const int tile = blockIdx.x & 63;
    const int h0   = (tile >> 3) << 4;
    const int w0   = (tile & 7) << 4;

    for (int i = tid; i < 800; i += 256) {
        int chn = (i >= 400) ? 1 : 0;
        int r  = i - chn * 400;
        int yy = r / 20;
        int xx = r - yy * 20;
        int h  = h0 + yy - 2;
        int w  = w0 + xx - 2;
        float v = 0.0f;
        if ((unsigned)h < 128u && (unsigned)w < 128u) {
            const float* src = chn ? masks : sig;
            v = src[(n << 14) + (h << 7) + w];
        }
        ls[chn][r] = v;
    }
    __syncthreads();

    const int tx = tid & 15;
    const int ty = tid >> 4;

    float accv = sb[0];
    #pragma unroll
    for (int chn = 0; chn < 2; ++chn)
        #pragma unroll
        for (int dy = 0; dy < 5; ++dy)
            #pragma unroll
            for (int dx = 0; dx < 5; ++dx)
                accv = fmaf(ls[chn][(ty + dy) * 20 + tx + dx],
                            sw[(chn * 5 + dy) * 5 + dx], accv);
    out[(n << 14) + ((h0 + ty) << 7) + (w0 + tx)] = accv;
}

extern "C" void kernel_launch(void* const* d_in, const int* in_sizes, int n_in,
                              void* d_out, int out_size, void* d_ws, size_t ws_size,
                              hipStream_t stream) {
    const float* emb     = (const float*)d_in[0];
    const float* inc     = (const float*)d_in[1];
    const float* masks   = (const float*)d_in[2];
    const float* conv_w  = (const float*)d_in[3];
    const float* conv_b  = (const float*)d_in[4];
    const float* bn_g    = (const float*)d_in[5];
    const float* bn_b    = (const float*)d_in[6];
    const float* bn_m    = (const float*)d_in[7];
    const float* bn_v    = (const float*)d_in[8];
    const float* sw      = (const float*)d_in[9];
    const float* sb      = (const float*)d_in[10];
    float*  out   = (float*)d_out;
    float*  sig   = (float*)d_ws;
    ushort* bfrag = (ushort*)((char*)d_ws + BFRAG_OFF);
    float*  shb   = (float*)((char*)d_ws + SH_OFF);
    float*  hdp   = (float*)((char*)d_ws + HDP_OFF);

    prep_kernel<<<54, 256, 0, stream>>>(conv_w, conv_b, bn_g, bn_b, bn_m, bn_v,
                                        inc, bfrag, shb, hdp);
    fused_main_kernel<<<512, 256, 0, stream>>>(emb, bfrag, shb, hdp, sig);
    smooth_kernel<<<2048, 256, 0, stream>>>(sig, masks, sw, sb, out);
}